// Round 18
// baseline (628.264 us; speedup 1.0000x reference)
//
#include <hip/hip_runtime.h>
#include <hip/hip_bf16.h>

#define TQ 2048
#define HIDDEN 1024
#define NB 4
#define NH 16
#define DH 64
#define BHN (NB*NH)   // 64
#define LOG2E 1.44269504f

typedef __attribute__((ext_vector_type(4))) float f32x4;
typedef __attribute__((ext_vector_type(8))) short s16x8;

#if __has_builtin(__builtin_amdgcn_exp2f)
#define EXP2(x) __builtin_amdgcn_exp2f(x)
#else
#define EXP2(x) exp2f(x)
#endif

__device__ inline unsigned short f2bf(float f) {
    union { float f; unsigned int u; } x; x.f = f;
    unsigned int r = x.u + 0x7fffu + ((x.u >> 16) & 1u);
    return (unsigned short)(r >> 16);
}

__device__ inline unsigned int pkbf(float a, float b) {
    __hip_bfloat162 h = __float22bfloat162_rn(make_float2(a, b));
    return *reinterpret_cast<unsigned int*>(&h);
}

union PBU { uint4 u4; s16x8 v; };

// async global->LDS, 16B per lane; lds dst must be wave-uniform base
#define GLL16(gsrc, ldst) \
    __builtin_amdgcn_global_load_lds( \
        (const __attribute__((address_space(1))) unsigned int*)(gsrc), \
        (__attribute__((address_space(3))) unsigned int*)(ldst), 16, 0, 0)

// ---------------------------------------------------------------------------
// Weight transpose+convert + mask prep fused: z in {0..3}: Wt[n][k]=bf16(W[k][n]);
// z==4: maskAndB ushort [4][2048] in pb-slot-PERMUTED order (0xFFFF keep / 0).
// ---------------------------------------------------------------------------
__global__ __launch_bounds__(256) void wt_kernel(const float* W0, const float* W1,
                                                 const float* W2, const float* W3,
                                                 unsigned short* Wt,
                                                 const int* __restrict__ pad,
                                                 unsigned short* __restrict__ maskAndB) {
    if (blockIdx.z == 4) {
        int lin = blockIdx.y * 16 + blockIdx.x;
        if (lin < 32) {
            int p = lin * 256 + threadIdx.x;   // 0..8191
            int r = p >> 11, off = p & 2047;
            int o6 = off & 63;
            int ks = o6 >> 5, k32 = o6 & 31;
            int lg = k32 >> 3, j = k32 & 7;
            int key = (off & ~63) | (ks * 32 + ((j >> 2) << 4) + (lg << 2) + (j & 3));
            maskAndB[p] = pad[r * 2048 + key] ? (unsigned short)0 : (unsigned short)0xFFFF;
        }
        return;
    }
    const float* W = (blockIdx.z == 0) ? W0 : (blockIdx.z == 1) ? W1
                    : (blockIdx.z == 2) ? W2 : W3;
    unsigned short* out = Wt + (size_t)blockIdx.z * HIDDEN * HIDDEN;
    __shared__ float tile[64][68];
    int t = threadIdx.x;
    int k0 = blockIdx.y * 64, n0 = blockIdx.x * 64;
#pragma unroll
    for (int i = 0; i < 4; i++) {
        int r = (t >> 4) + i * 16;
        int c = (t & 15) * 4;
        float4 v = *(const float4*)(W + (size_t)(k0 + r) * HIDDEN + n0 + c);
        tile[r][c] = v.x; tile[r][c+1] = v.y; tile[r][c+2] = v.z; tile[r][c+3] = v.w;
    }
    __syncthreads();
#pragma unroll
    for (int i = 0; i < 4; i++) {
        int n = (t >> 4) + i * 16;
        int kc = (t & 15) * 4;
        ushort4 o;
        o.x = f2bf(tile[kc+0][n]); o.y = f2bf(tile[kc+1][n]);
        o.z = f2bf(tile[kc+2][n]); o.w = f2bf(tile[kc+3][n]);
        *(ushort4*)(out + (size_t)(n0 + n) * HIDDEN + k0 + kc) = o;
    }
}

// ---------------------------------------------------------------------------
// Projection GEMM, BK=64 (R12-proven): A f32 [8192][1024] x Wt bf16 [n][k].
// 128x128 tile, grid (8,64). A staged f32 (32KB) via global_load_lds with
// pre-swizzled source (16 slots/row, slot^(row&15)); B bf16 (16KB,
// 8 slots/row, slot^(row&7)). Fragments cvt f32->bf16 on read.
// vt=0: out bf16 head-split [B*H][T][D], scaled
// vt=1: out bf16 head-split transposed [B*H][D][T]
// ---------------------------------------------------------------------------
__global__ __launch_bounds__(256) void gemm_proj(const float* __restrict__ A,
                                                 const unsigned short* __restrict__ Bt,
                                                 unsigned short* __restrict__ outb,
                                                 float scale, int vt) {
    __shared__ alignas(16) float As[128 * 64];            // 32 KB
    __shared__ alignas(16) unsigned short Bs[128 * 64];   // 16 KB
    const int t = threadIdx.x;
    const int wave = t >> 6, lane = t & 63;
    const int wr = wave >> 1, wc = wave & 1;
    const int lr = lane & 15, lg = lane >> 4;
    const int linear = blockIdx.x + 8 * blockIdx.y;          // 0..511
    const int tile = ((linear & 7) << 6) | (linear >> 3);
    const int m0 = (tile >> 3) * 128, n0 = (tile & 7) * 128;

    size_t gA[8];
#pragma unroll
    for (int i = 0; i < 8; i++) {
        int f = i * 256 + t;
        int row = f >> 4, sg = (f & 15) ^ (row & 15);
        gA[i] = (size_t)(m0 + row) * HIDDEN + sg * 4;
    }
    size_t gB[4];
#pragma unroll
    for (int i = 0; i < 4; i++) {
        int f = i * 256 + t;
        int row = f >> 3, sg = (f & 7) ^ (row & 7);
        gB[i] = (size_t)(n0 + row) * HIDDEN + sg * 8;
    }

    f32x4 acc[4][4] = {};

    for (int k0 = 0; k0 < HIDDEN; k0 += 64) {
        __syncthreads();
#pragma unroll
        for (int i = 0; i < 8; i++)
            GLL16(A + gA[i] + k0, &As[(size_t)(i * 256 + wave * 64) * 4]);
#pragma unroll
        for (int i = 0; i < 4; i++)
            GLL16(Bt + gB[i] + k0, &Bs[(size_t)(i * 256 + wave * 64) * 8]);
        __syncthreads();
#pragma unroll
        for (int q = 0; q < 2; q++) {
            s16x8 af[4], bfr[4];
#pragma unroll
            for (int mi = 0; mi < 4; mi++) {
                int row = wr * 64 + mi * 16 + lr;
                int s0 = (q * 8 + lg * 2) ^ (row & 15);
                int s1 = (q * 8 + lg * 2 + 1) ^ (row & 15);
                float4 a0 = *(const float4*)(&As[row * 64 + s0 * 4]);
                float4 a1 = *(const float4*)(&As[row * 64 + s1 * 4]);
                PBU u;
                u.u4.x = pkbf(a0.x, a0.y); u.u4.y = pkbf(a0.z, a0.w);
                u.u4.z = pkbf(a1.x, a1.y); u.u4.w = pkbf(a1.z, a1.w);
                af[mi] = u.v;
            }
#pragma unroll
            for (int ni = 0; ni < 4; ni++) {
                int row = wc * 64 + ni * 16 + lr;
                int s = (q * 4 + lg) ^ (row & 7);
                bfr[ni] = *(const s16x8*)(&Bs[row * 64 + s * 8]);
            }
#pragma unroll
            for (int mi = 0; mi < 4; mi++)
#pragma unroll
                for (int ni = 0; ni < 4; ni++)
                    acc[mi][ni] = __builtin_amdgcn_mfma_f32_16x16x32_bf16(af[mi], bfr[ni], acc[mi][ni], 0, 0, 0);
        }
    }

    if (vt == 0) {
#pragma unroll
        for (int mi = 0; mi < 4; mi++)
#pragma unroll
            for (int ni = 0; ni < 4; ni++)
#pragma unroll
                for (int j = 0; j < 4; j++) {
                    int m = m0 + wr * 64 + mi * 16 + lg * 4 + j;
                    int n = n0 + wc * 64 + ni * 16 + lr;
                    int b = m >> 11, tt = m & (TQ - 1);
                    int h = n >> 6, d = n & 63;
                    outb[((size_t)(b * NH + h) * TQ + tt) * DH + d] = f2bf(acc[mi][ni][j] * scale);
                }
    } else {
#pragma unroll
        for (int mi = 0; mi < 4; mi++)
#pragma unroll
            for (int ni = 0; ni < 4; ni++) {
                int m = m0 + wr * 64 + mi * 16 + lg * 4;
                int n = n0 + wc * 64 + ni * 16 + lr;
                int b = m >> 11, tt = m & (TQ - 1);
                int h = n >> 6, d = n & 63;
                ushort4 pk;
                pk.x = f2bf(acc[mi][ni][0] * scale);
                pk.y = f2bf(acc[mi][ni][1] * scale);
                pk.z = f2bf(acc[mi][ni][2] * scale);
                pk.w = f2bf(acc[mi][ni][3] * scale);
                *(ushort4*)(outb + ((size_t)(b * NH + h) * DH + d) * TQ + tt) = pk;
            }
    }
}

// ---------------------------------------------------------------------------
// Final GEMM, BK=64 (R12-proven): A bf16 [8192][1024] x Wt bf16 -> out f32.
// ---------------------------------------------------------------------------
__global__ __launch_bounds__(256) void gemm_out(const unsigned short* __restrict__ A,
                                                const unsigned short* __restrict__ Bt,
                                                float* __restrict__ out) {
    __shared__ alignas(16) unsigned short As[128 * 64];   // 16 KB
    __shared__ alignas(16) unsigned short Bs[128 * 64];   // 16 KB
    const int t = threadIdx.x;
    const int wave = t >> 6, lane = t & 63;
    const int wr = wave >> 1, wc = wave & 1;
    const int lr = lane & 15, lg = lane >> 4;
    const int linear = blockIdx.x + 8 * blockIdx.y;
    const int tile = ((linear & 7) << 6) | (linear >> 3);
    const int m0 = (tile >> 3) * 128, n0 = (tile & 7) * 128;

    size_t gA[4], gB[4];
#pragma unroll
    for (int i = 0; i < 4; i++) {
        int f = i * 256 + t;
        int row = f >> 3, sg = (f & 7) ^ (row & 7);
        gA[i] = (size_t)(m0 + row) * HIDDEN + sg * 8;
        gB[i] = (size_t)(n0 + row) * HIDDEN + sg * 8;
    }

    f32x4 acc[4][4] = {};

    for (int k0 = 0; k0 < HIDDEN; k0 += 64) {
        __syncthreads();
#pragma unroll
        for (int i = 0; i < 4; i++) {
            GLL16(A + gA[i] + k0, &As[(size_t)(i * 256 + wave * 64) * 8]);
            GLL16(Bt + gB[i] + k0, &Bs[(size_t)(i * 256 + wave * 64) * 8]);
        }
        __syncthreads();
#pragma unroll
        for (int q = 0; q < 2; q++) {
            s16x8 af[4], bfr[4];
#pragma unroll
            for (int mi = 0; mi < 4; mi++) {
                int row = wr * 64 + mi * 16 + lr;
                int s = (q * 4 + lg) ^ (row & 7);
                af[mi] = *(const s16x8*)(&As[row * 64 + s * 8]);
            }
#pragma unroll
            for (int ni = 0; ni < 4; ni++) {
                int row = wc * 64 + ni * 16 + lr;
                int s = (q * 4 + lg) ^ (row & 7);
                bfr[ni] = *(const s16x8*)(&Bs[row * 64 + s * 8]);
            }
#pragma unroll
            for (int mi = 0; mi < 4; mi++)
#pragma unroll
                for (int ni = 0; ni < 4; ni++)
                    acc[mi][ni] = __builtin_amdgcn_mfma_f32_16x16x32_bf16(af[mi], bfr[ni], acc[mi][ni], 0, 0, 0);
        }
    }
#pragma unroll
    for (int mi = 0; mi < 4; mi++)
#pragma unroll
        for (int ni = 0; ni < 4; ni++)
#pragma unroll
            for (int j = 0; j < 4; j++) {
                int m = m0 + wr * 64 + mi * 16 + lg * 4 + j;
                int n = n0 + wc * 64 + ni * 16 + lr;
                out[(size_t)m * HIDDEN + n] = acc[mi][ni][j];
            }
}

// ---------------------------------------------------------------------------
// Flash attention v14: in-block key-split. 512 thr = 8 waves; waves 0-3
// (group 0) process keys 0..1023, waves 4-7 (group 1) keys 1024..2047, each
// group with its own dbuf K/V tiles (73.7KB total -> 2 blocks/CU = 16
// waves/CU, double R15 at IDENTICAL per-wave amortization u=4 and identical
// total staging/LDS/MFMA work; barriers per block halve). Fixed-shift
// softmax partials combine exactly: O=(O0+O1)/(s0+s1), via one LDS
// round-trip reusing the tile arrays. XCD-chunked bh swizzle, swapped QK,
// in-lane P packing, P-AND mask, ones-MFMA denominator.
// ---------------------------------------------------------------------------
__global__ __launch_bounds__(512, 4) void attn_kernel(
        const unsigned short* __restrict__ QP,
        const unsigned short* __restrict__ KP,
        const unsigned short* __restrict__ VT,
        const unsigned short* __restrict__ maskAndB,
        unsigned short* __restrict__ AO) {
    // SM layout (ushort): [0..3]*4608 = K tiles (g,buf), [4..7]*4608 = V tiles
    __shared__ alignas(16) unsigned short SM[8 * 64 * 72];   // 73.7 KB
    const int t = threadIdx.x, wave = t >> 6, lane = t & 63;
    const int grp = wave >> 2, wv = wave & 3;
    const int lr = lane & 15, lg = lane >> 4;
    const int linear = blockIdx.x + 8 * blockIdx.y;          // 0..511
    const int bh = ((linear & 7) << 3) | ((linear >> 3) & 7);
    const int qb = linear >> 6;                               // 0..7
    const int q0 = qb * 256 + wv * 64;
    const unsigned short* Qb = QP + (size_t)bh * TQ * DH;
    const unsigned short* Kb = KP + (size_t)bh * TQ * DH + (size_t)grp * 1024 * DH;
    const unsigned short* Vb = VT + (size_t)bh * DH * TQ;
    const unsigned short* mrow = maskAndB + (bh & (NB - 1)) * TQ + grp * 1024;

    const short ob = (short)0x3F80;                    // bf16 1.0
    const s16x8 ones = {ob, ob, ob, ob, ob, ob, ob, ob};

    s16x8 qf[4][2];
#pragma unroll
    for (int u = 0; u < 4; u++)
#pragma unroll
        for (int hh = 0; hh < 2; hh++)
            qf[u][hh] = *(const s16x8*)(Qb + (size_t)(q0 + u * 16 + lr) * DH + hh * 32 + lg * 8);

    // group-local staging: 2 K-chunks + 2 V-chunks per thread (256 thr/group)
    const int st = t & 255;
    const int c0 = st, c1 = 256 + st;
    const int sr0 = c0 >> 3, scl0 = (c0 & 7) * 8;
    const int sr1 = c1 >> 3, scl1 = (c1 & 7) * 8;
    const unsigned short* kA0 = Kb + sr0 * DH + scl0;
    const unsigned short* kA1 = Kb + sr1 * DH + scl1;
    const unsigned short* vA0 = Vb + (size_t)sr0 * TQ + grp * 1024 + scl0;
    const unsigned short* vA1 = Vb + (size_t)sr1 * TQ + grp * 1024 + scl1;
    const int ksO0 = sr0 * 72 + scl0, ksO1 = sr1 * 72 + scl1;
    const int cc0 = c0 & 7, cc1 = c1 & 7;
    const int vg0 = ((cc0 & 4) << 1) + ((cc0 & 1) << 2) + ((cc0 >> 1) & 1);
    const int vg1 = ((cc1 & 4) << 1) + ((cc1 & 1) << 2) + ((cc1 >> 1) & 1);
    const int vO0 = sr0 * 72 + vg0 * 4, vO1 = sr1 * 72 + vg1 * 4;

    unsigned short* Kt0 = SM + (size_t)((grp << 1) | 0) * 4608;
    unsigned short* Kt1 = SM + (size_t)((grp << 1) | 1) * 4608;
    unsigned short* Vt0 = SM + (size_t)(4 + ((grp << 1) | 0)) * 4608;
    unsigned short* Vt1 = SM + (size_t)(4 + ((grp << 1) | 1)) * 4608;

    uint4 kr0, kr1, vr0, vr1;
#define LOAD_TILE(kt_) do { \
        kr0 = *(const uint4*)(kA0 + (size_t)(kt_) * 4096); \
        kr1 = *(const uint4*)(kA1 + (size_t)(kt_) * 4096); \
        vr0 = *(const uint4*)(vA0 + (size_t)(kt_) * 64); \
        vr1 = *(const uint4*)(vA1 + (size_t)(kt_) * 64); \
    } while (0)
#define STORE_TILE(b_) do { \
        unsigned short* kd = (b_) ? Kt1 : Kt0; \
        unsigned short* vd = (b_) ? Vt1 : Vt0; \
        *(uint4*)(&kd[ksO0]) = kr0; \
        *(uint4*)(&kd[ksO1]) = kr1; \
        *(uint2*)(&vd[vO0])     = make_uint2(vr0.x, vr0.y); \
        *(uint2*)(&vd[vO0 + 8]) = make_uint2(vr0.z, vr0.w); \
        *(uint2*)(&vd[vO1])     = make_uint2(vr1.x, vr1.y); \
        *(uint2*)(&vd[vO1 + 8]) = make_uint2(vr1.z, vr1.w); \
    } while (0)

    f32x4 o[4][4] = {};
    f32x4 osum[4] = {};

    LOAD_TILE(0);
    STORE_TILE(0);

    const int NT = 1024 / 64;   // 16 per group
    for (int kt = 0; kt < NT; kt++) {
        __syncthreads();
        const int cur = kt & 1;
        if (kt + 1 < NT) LOAD_TILE(kt + 1);
        uint4 ma0 = *(const uint4*)(mrow + kt * 64 + lg * 8);
        uint4 ma1 = *(const uint4*)(mrow + kt * 64 + 32 + lg * 8);
        const unsigned short* Kh = cur ? Kt1 : Kt0;
        const unsigned short* Vh = cur ? Vt1 : Vt0;

        // S^T: z[u][ni][r], q=lr, k=ni*16+lg*4+r; kf shared across 4 u
        f32x4 z[4][4] = {};
#pragma unroll
        for (int ni = 0; ni < 4; ni++) {
            s16x8 kf0 = *(const s16x8*)(&Kh[(ni * 16 + lr) * 72 + lg * 8]);
            s16x8 kf1 = *(const s16x8*)(&Kh[(ni * 16 + lr) * 72 + 32 + lg * 8]);
#pragma unroll
            for (int u = 0; u < 4; u++) {
                z[u][ni] = __builtin_amdgcn_mfma_f32_16x16x32_bf16(kf0, qf[u][0], z[u][ni], 0, 0, 0);
                z[u][ni] = __builtin_amdgcn_mfma_f32_16x16x32_bf16(kf1, qf[u][1], z[u][ni], 0, 0, 0);
            }
        }

        // P = exp2(z) (fixed-shift softmax), pack in-lane, AND mask
        PBU pb[4][2];
#pragma unroll
        for (int u = 0; u < 4; u++) {
#pragma unroll
            for (int ni = 0; ni < 4; ni++)
#pragma unroll
                for (int rr = 0; rr < 4; rr++)
                    z[u][ni][rr] = EXP2(z[u][ni][rr]);
#pragma unroll
            for (int ks = 0; ks < 2; ks++) {
                pb[u][ks].u4.x = pkbf(z[u][2 * ks][0], z[u][2 * ks][1]);
                pb[u][ks].u4.y = pkbf(z[u][2 * ks][2], z[u][2 * ks][3]);
                pb[u][ks].u4.z = pkbf(z[u][2 * ks + 1][0], z[u][2 * ks + 1][1]);
                pb[u][ks].u4.w = pkbf(z[u][2 * ks + 1][2], z[u][2 * ks + 1][3]);
            }
            pb[u][0].u4.x &= ma0.x; pb[u][0].u4.y &= ma0.y;
            pb[u][0].u4.z &= ma0.z; pb[u][0].u4.w &= ma0.w;
            pb[u][1].u4.x &= ma1.x; pb[u][1].u4.y &= ma1.y;
            pb[u][1].u4.z &= ma1.z; pb[u][1].u4.w &= ma1.w;
        }

        // O^T += V^T x P^T ; denominator via const-ones MFMA (pb pre-masked)
#pragma unroll
        for (int di = 0; di < 4; di++)
#pragma unroll
            for (int ks = 0; ks < 2; ks++) {
                s16x8 vf = *(const s16x8*)(&Vh[(di * 16 + lr) * 72 + ks * 32 + lg * 8]);
#pragma unroll
                for (int u = 0; u < 4; u++)
                    o[u][di] = __builtin_amdgcn_mfma_f32_16x16x32_bf16(vf, pb[u][ks].v, o[u][di], 0, 0, 0);
            }
#pragma unroll
        for (int u = 0; u < 4; u++) {
            osum[u] = __builtin_amdgcn_mfma_f32_16x16x32_bf16(ones, pb[u][0].v, osum[u], 0, 0, 0);
            osum[u] = __builtin_amdgcn_mfma_f32_16x16x32_bf16(ones, pb[u][1].v, osum[u], 0, 0, 0);
        }

        if (kt + 1 < NT) STORE_TILE((kt + 1) & 1);
    }

    // combine partials: group 1 -> LDS (reuse SM), group 0 adds + writes AO.
    __syncthreads();
    float* cb = (float*)SM;
    const int cbase = (wv * 64 + lane) * 68;   // 68 f32 per lane slot
    if (grp == 1) {
#pragma unroll
        for (int u = 0; u < 4; u++) {
#pragma unroll
            for (int di = 0; di < 4; di++)
                *(float4*)(cb + cbase + u * 16 + di * 4) =
                    make_float4(o[u][di][0], o[u][di][1], o[u][di][2], o[u][di][3]);
        }
        float4 sv = make_float4(osum[0][0], osum[1][0], osum[2][0], osum[3][0]);
        *(float4*)(cb + cbase + 64) = sv;
    }
    __syncthreads();
    if (grp == 0) {
        const int b = bh >> 4, h = bh & 15;
        float4 sv = *(const float4*)(cb + cbase + 64);
        float stot[4] = {osum[0][0] + sv.x, osum[1][0] + sv.y,
                         osum[2][0] + sv.z, osum[3][0] + sv.w};
#pragma unroll
        for (int u = 0; u < 4; u++) {
            float inv = 1.f / stot[u];
            int tt = q0 + u * 16 + lr;
#pragma unroll
            for (int di = 0; di < 4; di++) {
                float4 p = *(const float4*)(cb + cbase + u * 16 + di * 4);
                uint2 w;
                w.x = pkbf((o[u][di][0] + p.x) * inv, (o[u][di][1] + p.y) * inv);
                w.y = pkbf((o[u][di][2] + p.z) * inv, (o[u][di][3] + p.w) * inv);
                *(uint2*)(AO + (size_t)(b * TQ + tt) * HIDDEN + h * 64 + di * 16 + lg * 4) = w;
            }
        }
    }
#undef LOAD_TILE
#undef STORE_TILE
}

// ---------------------------------------------------------------------------
extern "C" void kernel_launch(void* const* d_in, const int* in_sizes, int n_in,
                              void* d_out, int out_size, void* d_ws, size_t ws_size,
                              hipStream_t stream) {
    const float* q  = (const float*)d_in[0];
    const float* k  = (const float*)d_in[1];
    const float* v  = (const float*)d_in[2];
    const int* pad  = (const int*)d_in[3];
    const float* Wq = (const float*)d_in[4];
    const float* Wk = (const float*)d_in[5];
    const float* Wv = (const float*)d_in[6];
    const float* Wo = (const float*)d_in[7];
    float* out = (float*)d_out;

    // ws (bf16 elems): Wt 4M | AO 8.39M | QP | KP | VT | maskAndB
    unsigned short* ws = (unsigned short*)d_ws;
    unsigned short* Wt = ws;
    unsigned short* AO = ws + (size_t)4 * 1024 * 1024;
    unsigned short* QP = AO + (size_t)BHN * TQ * DH;
    unsigned short* KP = QP + (size_t)BHN * TQ * DH;
    unsigned short* VTb = KP + (size_t)BHN * TQ * DH;
    unsigned short* maskAndB = VTb + (size_t)BHN * TQ * DH;
    (void)ws_size; (void)in_sizes; (void)n_in; (void)out_size;

    dim3 b256(256);
    const dim3 gGemm(8, 64);
    wt_kernel<<<dim3(16, 16, 5), b256, 0, stream>>>(Wq, Wk, Wv, Wo, Wt, pad, maskAndB);
    gemm_proj<<<gGemm, b256, 0, stream>>>(q, Wt + (size_t)0 * 1024 * 1024, QP, 0.125f * LOG2E, 0);
    gemm_proj<<<gGemm, b256, 0, stream>>>(k, Wt + (size_t)1 * 1024 * 1024, KP, 1.0f, 0);
    gemm_proj<<<gGemm, b256, 0, stream>>>(v, Wt + (size_t)2 * 1024 * 1024, VTb, 1.0f, 1);
    attn_kernel<<<gGemm, dim3(512), 0, stream>>>(QP, KP, VTb, maskAndB, AO);
    gemm_out<<<gGemm, b256, 0, stream>>>(AO, Wt + (size_t)3 * 1024 * 1024, out);
}

// Round 19
// 203.755 us; speedup vs baseline: 3.0834x; 3.0834x over previous
//
#include <hip/hip_runtime.h>
#include <hip/hip_bf16.h>

#define TQ 2048
#define HIDDEN 1024
#define NB 4
#define NH 16
#define DH 64
#define BHN (NB*NH)   // 64
#define LOG2E 1.44269504f

typedef __attribute__((ext_vector_type(4))) float f32x4;
typedef __attribute__((ext_vector_type(8))) short s16x8;

#if __has_builtin(__builtin_amdgcn_exp2f)
#define EXP2(x) __builtin_amdgcn_exp2f(x)
#else
#define EXP2(x) exp2f(x)
#endif

__device__ inline unsigned short f2bf(float f) {
    union { float f; unsigned int u; } x; x.f = f;
    unsigned int r = x.u + 0x7fffu + ((x.u >> 16) & 1u);
    return (unsigned short)(r >> 16);
}

__device__ inline unsigned int pkbf(float a, float b) {
    __hip_bfloat162 h = __float22bfloat162_rn(make_float2(a, b));
    return *reinterpret_cast<unsigned int*>(&h);
}

union PBU { uint4 u4; s16x8 v; };

// async global->LDS, 16B per lane; lds dst must be wave-uniform base
#define GLL16(gsrc, ldst) \
    __builtin_amdgcn_global_load_lds( \
        (const __attribute__((address_space(1))) unsigned int*)(gsrc), \
        (__attribute__((address_space(3))) unsigned int*)(ldst), 16, 0, 0)

// ---------------------------------------------------------------------------
// Weight transpose+convert + mask prep fused: z in {0..3}: Wt[n][k]=bf16(W[k][n]);
// z==4: maskAndB ushort [4][2048] in pb-slot-PERMUTED order (0xFFFF keep / 0).
// ---------------------------------------------------------------------------
__global__ __launch_bounds__(256) void wt_kernel(const float* W0, const float* W1,
                                                 const float* W2, const float* W3,
                                                 unsigned short* Wt,
                                                 const int* __restrict__ pad,
                                                 unsigned short* __restrict__ maskAndB) {
    if (blockIdx.z == 4) {
        int lin = blockIdx.y * 16 + blockIdx.x;
        if (lin < 32) {
            int p = lin * 256 + threadIdx.x;   // 0..8191
            int r = p >> 11, off = p & 2047;
            int o6 = off & 63;
            int ks = o6 >> 5, k32 = o6 & 31;
            int lg = k32 >> 3, j = k32 & 7;
            int key = (off & ~63) | (ks * 32 + ((j >> 2) << 4) + (lg << 2) + (j & 3));
            maskAndB[p] = pad[r * 2048 + key] ? (unsigned short)0 : (unsigned short)0xFFFF;
        }
        return;
    }
    const float* W = (blockIdx.z == 0) ? W0 : (blockIdx.z == 1) ? W1
                    : (blockIdx.z == 2) ? W2 : W3;
    unsigned short* out = Wt + (size_t)blockIdx.z * HIDDEN * HIDDEN;
    __shared__ float tile[64][68];
    int t = threadIdx.x;
    int k0 = blockIdx.y * 64, n0 = blockIdx.x * 64;
#pragma unroll
    for (int i = 0; i < 4; i++) {
        int r = (t >> 4) + i * 16;
        int c = (t & 15) * 4;
        float4 v = *(const float4*)(W + (size_t)(k0 + r) * HIDDEN + n0 + c);
        tile[r][c] = v.x; tile[r][c+1] = v.y; tile[r][c+2] = v.z; tile[r][c+3] = v.w;
    }
    __syncthreads();
#pragma unroll
    for (int i = 0; i < 4; i++) {
        int n = (t >> 4) + i * 16;
        int kc = (t & 15) * 4;
        ushort4 o;
        o.x = f2bf(tile[kc+0][n]); o.y = f2bf(tile[kc+1][n]);
        o.z = f2bf(tile[kc+2][n]); o.w = f2bf(tile[kc+3][n]);
        *(ushort4*)(out + (size_t)(n0 + n) * HIDDEN + k0 + kc) = o;
    }
}

// ---------------------------------------------------------------------------
// Projection GEMM, BK=64 (R12-proven): A f32 [8192][1024] x Wt bf16 [n][k].
// 128x128 tile, grid (8,64). A staged f32 (32KB) via global_load_lds with
// pre-swizzled source (16 slots/row, slot^(row&15)); B bf16 (16KB,
// 8 slots/row, slot^(row&7)). Fragments cvt f32->bf16 on read.
// vt=0: out bf16 head-split [B*H][T][D], scaled
// vt=1: out bf16 head-split transposed [B*H][D][T]
// ---------------------------------------------------------------------------
__global__ __launch_bounds__(256) void gemm_proj(const float* __restrict__ A,
                                                 const unsigned short* __restrict__ Bt,
                                                 unsigned short* __restrict__ outb,
                                                 float scale, int vt) {
    __shared__ alignas(16) float As[128 * 64];            // 32 KB
    __shared__ alignas(16) unsigned short Bs[128 * 64];   // 16 KB
    const int t = threadIdx.x;
    const int wave = t >> 6, lane = t & 63;
    const int wr = wave >> 1, wc = wave & 1;
    const int lr = lane & 15, lg = lane >> 4;
    const int linear = blockIdx.x + 8 * blockIdx.y;          // 0..511
    const int tile = ((linear & 7) << 6) | (linear >> 3);
    const int m0 = (tile >> 3) * 128, n0 = (tile & 7) * 128;

    size_t gA[8];
#pragma unroll
    for (int i = 0; i < 8; i++) {
        int f = i * 256 + t;
        int row = f >> 4, sg = (f & 15) ^ (row & 15);
        gA[i] = (size_t)(m0 + row) * HIDDEN + sg * 4;
    }
    size_t gB[4];
#pragma unroll
    for (int i = 0; i < 4; i++) {
        int f = i * 256 + t;
        int row = f >> 3, sg = (f & 7) ^ (row & 7);
        gB[i] = (size_t)(n0 + row) * HIDDEN + sg * 8;
    }

    f32x4 acc[4][4] = {};

    for (int k0 = 0; k0 < HIDDEN; k0 += 64) {
        __syncthreads();
#pragma unroll
        for (int i = 0; i < 8; i++)
            GLL16(A + gA[i] + k0, &As[(size_t)(i * 256 + wave * 64) * 4]);
#pragma unroll
        for (int i = 0; i < 4; i++)
            GLL16(Bt + gB[i] + k0, &Bs[(size_t)(i * 256 + wave * 64) * 8]);
        __syncthreads();
#pragma unroll
        for (int q = 0; q < 2; q++) {
            s16x8 af[4], bfr[4];
#pragma unroll
            for (int mi = 0; mi < 4; mi++) {
                int row = wr * 64 + mi * 16 + lr;
                int s0 = (q * 8 + lg * 2) ^ (row & 15);
                int s1 = (q * 8 + lg * 2 + 1) ^ (row & 15);
                float4 a0 = *(const float4*)(&As[row * 64 + s0 * 4]);
                float4 a1 = *(const float4*)(&As[row * 64 + s1 * 4]);
                PBU u;
                u.u4.x = pkbf(a0.x, a0.y); u.u4.y = pkbf(a0.z, a0.w);
                u.u4.z = pkbf(a1.x, a1.y); u.u4.w = pkbf(a1.z, a1.w);
                af[mi] = u.v;
            }
#pragma unroll
            for (int ni = 0; ni < 4; ni++) {
                int row = wc * 64 + ni * 16 + lr;
                int s = (q * 4 + lg) ^ (row & 7);
                bfr[ni] = *(const s16x8*)(&Bs[row * 64 + s * 8]);
            }
#pragma unroll
            for (int mi = 0; mi < 4; mi++)
#pragma unroll
                for (int ni = 0; ni < 4; ni++)
                    acc[mi][ni] = __builtin_amdgcn_mfma_f32_16x16x32_bf16(af[mi], bfr[ni], acc[mi][ni], 0, 0, 0);
        }
    }

    if (vt == 0) {
#pragma unroll
        for (int mi = 0; mi < 4; mi++)
#pragma unroll
            for (int ni = 0; ni < 4; ni++)
#pragma unroll
                for (int j = 0; j < 4; j++) {
                    int m = m0 + wr * 64 + mi * 16 + lg * 4 + j;
                    int n = n0 + wc * 64 + ni * 16 + lr;
                    int b = m >> 11, tt = m & (TQ - 1);
                    int h = n >> 6, d = n & 63;
                    outb[((size_t)(b * NH + h) * TQ + tt) * DH + d] = f2bf(acc[mi][ni][j] * scale);
                }
    } else {
#pragma unroll
        for (int mi = 0; mi < 4; mi++)
#pragma unroll
            for (int ni = 0; ni < 4; ni++) {
                int m = m0 + wr * 64 + mi * 16 + lg * 4;
                int n = n0 + wc * 64 + ni * 16 + lr;
                int b = m >> 11, tt = m & (TQ - 1);
                int h = n >> 6, d = n & 63;
                ushort4 pk;
                pk.x = f2bf(acc[mi][ni][0] * scale);
                pk.y = f2bf(acc[mi][ni][1] * scale);
                pk.z = f2bf(acc[mi][ni][2] * scale);
                pk.w = f2bf(acc[mi][ni][3] * scale);
                *(ushort4*)(outb + ((size_t)(b * NH + h) * DH + d) * TQ + tt) = pk;
            }
    }
}

// ---------------------------------------------------------------------------
// Final GEMM, BK=64 (R12-proven): A bf16 [8192][1024] x Wt bf16 -> out f32.
// ---------------------------------------------------------------------------
__global__ __launch_bounds__(256) void gemm_out(const unsigned short* __restrict__ A,
                                                const unsigned short* __restrict__ Bt,
                                                float* __restrict__ out) {
    __shared__ alignas(16) unsigned short As[128 * 64];   // 16 KB
    __shared__ alignas(16) unsigned short Bs[128 * 64];   // 16 KB
    const int t = threadIdx.x;
    const int wave = t >> 6, lane = t & 63;
    const int wr = wave >> 1, wc = wave & 1;
    const int lr = lane & 15, lg = lane >> 4;
    const int linear = blockIdx.x + 8 * blockIdx.y;
    const int tile = ((linear & 7) << 6) | (linear >> 3);
    const int m0 = (tile >> 3) * 128, n0 = (tile & 7) * 128;

    size_t gA[4], gB[4];
#pragma unroll
    for (int i = 0; i < 4; i++) {
        int f = i * 256 + t;
        int row = f >> 3, sg = (f & 7) ^ (row & 7);
        gA[i] = (size_t)(m0 + row) * HIDDEN + sg * 8;
        gB[i] = (size_t)(n0 + row) * HIDDEN + sg * 8;
    }

    f32x4 acc[4][4] = {};

    for (int k0 = 0; k0 < HIDDEN; k0 += 64) {
        __syncthreads();
#pragma unroll
        for (int i = 0; i < 4; i++) {
            GLL16(A + gA[i] + k0, &As[(size_t)(i * 256 + wave * 64) * 8]);
            GLL16(Bt + gB[i] + k0, &Bs[(size_t)(i * 256 + wave * 64) * 8]);
        }
        __syncthreads();
#pragma unroll
        for (int q = 0; q < 2; q++) {
            s16x8 af[4], bfr[4];
#pragma unroll
            for (int mi = 0; mi < 4; mi++) {
                int row = wr * 64 + mi * 16 + lr;
                int s = (q * 4 + lg) ^ (row & 7);
                af[mi] = *(const s16x8*)(&As[row * 64 + s * 8]);
            }
#pragma unroll
            for (int ni = 0; ni < 4; ni++) {
                int row = wc * 64 + ni * 16 + lr;
                int s = (q * 4 + lg) ^ (row & 7);
                bfr[ni] = *(const s16x8*)(&Bs[row * 64 + s * 8]);
            }
#pragma unroll
            for (int mi = 0; mi < 4; mi++)
#pragma unroll
                for (int ni = 0; ni < 4; ni++)
                    acc[mi][ni] = __builtin_amdgcn_mfma_f32_16x16x32_bf16(af[mi], bfr[ni], acc[mi][ni], 0, 0, 0);
        }
    }
#pragma unroll
    for (int mi = 0; mi < 4; mi++)
#pragma unroll
        for (int ni = 0; ni < 4; ni++)
#pragma unroll
            for (int j = 0; j < 4; j++) {
                int m = m0 + wr * 64 + mi * 16 + lg * 4 + j;
                int n = n0 + wc * 64 + ni * 16 + lr;
                out[(size_t)m * HIDDEN + n] = acc[mi][ni][j];
            }
}

// ---------------------------------------------------------------------------
// Flash attention v14b: in-block key-split, FIXED register cap (512,2) ->
// 256-VGPR budget, no spill (R18's (512,4) capped at 128 and spilled to
// scratch: 1.2GB writes). Waves 0-3 keys 0..1023, waves 4-7 keys 1024..2047,
// own dbuf tiles (73.7KB); u=4 amortization identical to R15. Fixed-shift
// partials combine exactly via one LDS round-trip. XCD-chunked bh swizzle,
// swapped QK, in-lane P packing, P-AND mask, ones-MFMA denominator.
// ---------------------------------------------------------------------------
__global__ __launch_bounds__(512, 2) void attn_kernel(
        const unsigned short* __restrict__ QP,
        const unsigned short* __restrict__ KP,
        const unsigned short* __restrict__ VT,
        const unsigned short* __restrict__ maskAndB,
        unsigned short* __restrict__ AO) {
    __shared__ alignas(16) unsigned short SM[8 * 64 * 72];   // 73.7 KB
    const int t = threadIdx.x, wave = t >> 6, lane = t & 63;
    const int grp = wave >> 2, wv = wave & 3;
    const int lr = lane & 15, lg = lane >> 4;
    const int linear = blockIdx.x + 8 * blockIdx.y;          // 0..511
    const int bh = ((linear & 7) << 3) | ((linear >> 3) & 7);
    const int qb = linear >> 6;                               // 0..7
    const int q0 = qb * 256 + wv * 64;
    const unsigned short* Qb = QP + (size_t)bh * TQ * DH;
    const unsigned short* Kb = KP + (size_t)bh * TQ * DH + (size_t)grp * 1024 * DH;
    const unsigned short* Vb = VT + (size_t)bh * DH * TQ;
    const unsigned short* mrow = maskAndB + (bh & (NB - 1)) * TQ + grp * 1024;

    const short ob = (short)0x3F80;                    // bf16 1.0
    const s16x8 ones = {ob, ob, ob, ob, ob, ob, ob, ob};

    s16x8 qf[4][2];
#pragma unroll
    for (int u = 0; u < 4; u++)
#pragma unroll
        for (int hh = 0; hh < 2; hh++)
            qf[u][hh] = *(const s16x8*)(Qb + (size_t)(q0 + u * 16 + lr) * DH + hh * 32 + lg * 8);

    // group-local staging: 2 K-chunks + 2 V-chunks per thread (256 thr/group)
    const int st = t & 255;
    const int c0 = st, c1 = 256 + st;
    const int sr0 = c0 >> 3, scl0 = (c0 & 7) * 8;
    const int sr1 = c1 >> 3, scl1 = (c1 & 7) * 8;
    const unsigned short* kA0 = Kb + sr0 * DH + scl0;
    const unsigned short* kA1 = Kb + sr1 * DH + scl1;
    const unsigned short* vA0 = Vb + (size_t)sr0 * TQ + grp * 1024 + scl0;
    const unsigned short* vA1 = Vb + (size_t)sr1 * TQ + grp * 1024 + scl1;
    const int ksO0 = sr0 * 72 + scl0, ksO1 = sr1 * 72 + scl1;
    const int cc0 = c0 & 7, cc1 = c1 & 7;
    const int vg0 = ((cc0 & 4) << 1) + ((cc0 & 1) << 2) + ((cc0 >> 1) & 1);
    const int vg1 = ((cc1 & 4) << 1) + ((cc1 & 1) << 2) + ((cc1 >> 1) & 1);
    const int vO0 = sr0 * 72 + vg0 * 4, vO1 = sr1 * 72 + vg1 * 4;

    unsigned short* Kt0 = SM + (size_t)((grp << 1) | 0) * 4608;
    unsigned short* Kt1 = SM + (size_t)((grp << 1) | 1) * 4608;
    unsigned short* Vt0 = SM + (size_t)(4 + ((grp << 1) | 0)) * 4608;
    unsigned short* Vt1 = SM + (size_t)(4 + ((grp << 1) | 1)) * 4608;

    uint4 kr0, kr1, vr0, vr1;
#define LOAD_TILE(kt_) do { \
        kr0 = *(const uint4*)(kA0 + (size_t)(kt_) * 4096); \
        kr1 = *(const uint4*)(kA1 + (size_t)(kt_) * 4096); \
        vr0 = *(const uint4*)(vA0 + (size_t)(kt_) * 64); \
        vr1 = *(const uint4*)(vA1 + (size_t)(kt_) * 64); \
    } while (0)
#define STORE_TILE(b_) do { \
        unsigned short* kd = (b_) ? Kt1 : Kt0; \
        unsigned short* vd = (b_) ? Vt1 : Vt0; \
        *(uint4*)(&kd[ksO0]) = kr0; \
        *(uint4*)(&kd[ksO1]) = kr1; \
        *(uint2*)(&vd[vO0])     = make_uint2(vr0.x, vr0.y); \
        *(uint2*)(&vd[vO0 + 8]) = make_uint2(vr0.z, vr0.w); \
        *(uint2*)(&vd[vO1])     = make_uint2(vr1.x, vr1.y); \
        *(uint2*)(&vd[vO1 + 8]) = make_uint2(vr1.z, vr1.w); \
    } while (0)

    f32x4 o[4][4] = {};
    f32x4 osum[4] = {};

    LOAD_TILE(0);
    STORE_TILE(0);

    const int NT = 1024 / 64;   // 16 per group
    for (int kt = 0; kt < NT; kt++) {
        __syncthreads();
        const int cur = kt & 1;
        if (kt + 1 < NT) LOAD_TILE(kt + 1);
        uint4 ma0 = *(const uint4*)(mrow + kt * 64 + lg * 8);
        uint4 ma1 = *(const uint4*)(mrow + kt * 64 + 32 + lg * 8);
        const unsigned short* Kh = cur ? Kt1 : Kt0;
        const unsigned short* Vh = cur ? Vt1 : Vt0;

        // S^T: z[u][ni][r], q=lr, k=ni*16+lg*4+r; kf shared across 4 u
        f32x4 z[4][4] = {};
#pragma unroll
        for (int ni = 0; ni < 4; ni++) {
            s16x8 kf0 = *(const s16x8*)(&Kh[(ni * 16 + lr) * 72 + lg * 8]);
            s16x8 kf1 = *(const s16x8*)(&Kh[(ni * 16 + lr) * 72 + 32 + lg * 8]);
#pragma unroll
            for (int u = 0; u < 4; u++) {
                z[u][ni] = __builtin_amdgcn_mfma_f32_16x16x32_bf16(kf0, qf[u][0], z[u][ni], 0, 0, 0);
                z[u][ni] = __builtin_amdgcn_mfma_f32_16x16x32_bf16(kf1, qf[u][1], z[u][ni], 0, 0, 0);
            }
        }

        // P = exp2(z) (fixed-shift softmax), pack in-lane, AND mask
        PBU pb[4][2];
#pragma unroll
        for (int u = 0; u < 4; u++) {
#pragma unroll
            for (int ni = 0; ni < 4; ni++)
#pragma unroll
                for (int rr = 0; rr < 4; rr++)
                    z[u][ni][rr] = EXP2(z[u][ni][rr]);
#pragma unroll
            for (int ks = 0; ks < 2; ks++) {
                pb[u][ks].u4.x = pkbf(z[u][2 * ks][0], z[u][2 * ks][1]);
                pb[u][ks].u4.y = pkbf(z[u][2 * ks][2], z[u][2 * ks][3]);
                pb[u][ks].u4.z = pkbf(z[u][2 * ks + 1][0], z[u][2 * ks + 1][1]);
                pb[u][ks].u4.w = pkbf(z[u][2 * ks + 1][2], z[u][2 * ks + 1][3]);
            }
            pb[u][0].u4.x &= ma0.x; pb[u][0].u4.y &= ma0.y;
            pb[u][0].u4.z &= ma0.z; pb[u][0].u4.w &= ma0.w;
            pb[u][1].u4.x &= ma1.x; pb[u][1].u4.y &= ma1.y;
            pb[u][1].u4.z &= ma1.z; pb[u][1].u4.w &= ma1.w;
        }

        // O^T += V^T x P^T ; denominator via const-ones MFMA (pb pre-masked)
#pragma unroll
        for (int di = 0; di < 4; di++)
#pragma unroll
            for (int ks = 0; ks < 2; ks++) {
                s16x8 vf = *(const s16x8*)(&Vh[(di * 16 + lr) * 72 + ks * 32 + lg * 8]);
#pragma unroll
                for (int u = 0; u < 4; u++)
                    o[u][di] = __builtin_amdgcn_mfma_f32_16x16x32_bf16(vf, pb[u][ks].v, o[u][di], 0, 0, 0);
            }
#pragma unroll
        for (int u = 0; u < 4; u++) {
            osum[u] = __builtin_amdgcn_mfma_f32_16x16x32_bf16(ones, pb[u][0].v, osum[u], 0, 0, 0);
            osum[u] = __builtin_amdgcn_mfma_f32_16x16x32_bf16(ones, pb[u][1].v, osum[u], 0, 0, 0);
        }

        if (kt + 1 < NT) STORE_TILE((kt + 1) & 1);
    }

    // combine partials: group 1 -> LDS (reuse SM), group 0 adds + writes AO.
    __syncthreads();
    float* cb = (float*)SM;
    const int cbase = (wv * 64 + lane) * 68;   // 68 f32 per lane slot
    if (grp == 1) {
#pragma unroll
        for (int u = 0; u < 4; u++) {
#pragma unroll
            for (int di = 0; di < 4; di++)
                *(float4*)(cb + cbase + u * 16 + di * 4) =
                    make_float4(o[u][di][0], o[u][di][1], o[u][di][2], o[u][di][3]);
        }
        float4 sv = make_float4(osum[0][0], osum[1][0], osum[2][0], osum[3][0]);
        *(float4*)(cb + cbase + 64) = sv;
    }
    __syncthreads();
    if (grp == 0) {
        const int b = bh >> 4, h = bh & 15;
        float4 sv = *(const float4*)(cb + cbase + 64);
        float stot[4] = {osum[0][0] + sv.x, osum[1][0] + sv.y,
                         osum[2][0] + sv.z, osum[3][0] + sv.w};
#pragma unroll
        for (int u = 0; u < 4; u++) {
            float inv = 1.f / stot[u];
            int tt = q0 + u * 16 + lr;
#pragma unroll
            for (int di = 0; di < 4; di++) {
                float4 p = *(const float4*)(cb + cbase + u * 16 + di * 4);
                uint2 w;
                w.x = pkbf((o[u][di][0] + p.x) * inv, (o[u][di][1] + p.y) * inv);
                w.y = pkbf((o[u][di][2] + p.z) * inv, (o[u][di][3] + p.w) * inv);
                *(uint2*)(AO + (size_t)(b * TQ + tt) * HIDDEN + h * 64 + di * 16 + lg * 4) = w;
            }
        }
    }
#undef LOAD_TILE
#undef STORE_TILE
}

// ---------------------------------------------------------------------------
extern "C" void kernel_launch(void* const* d_in, const int* in_sizes, int n_in,
                              void* d_out, int out_size, void* d_ws, size_t ws_size,
                              hipStream_t stream) {
    const float* q  = (const float*)d_in[0];
    const float* k  = (const float*)d_in[1];
    const float* v  = (const float*)d_in[2];
    const int* pad  = (const int*)d_in[3];
    const float* Wq = (const float*)d_in[4];
    const float* Wk = (const float*)d_in[5];
    const float* Wv = (const float*)d_in[6];
    const float* Wo = (const float*)d_in[7];
    float* out = (float*)d_out;

    // ws (bf16 elems): Wt 4M | AO 8.39M | QP | KP | VT | maskAndB
    unsigned short* ws = (unsigned short*)d_ws;
    unsigned short* Wt = ws;
    unsigned short* AO = ws + (size_t)4 * 1024 * 1024;
    unsigned short* QP = AO + (size_t)BHN * TQ * DH;
    unsigned short* KP = QP + (size_t)BHN * TQ * DH;
    unsigned short* VTb = KP + (size_t)BHN * TQ * DH;
    unsigned short* maskAndB = VTb + (size_t)BHN * TQ * DH;
    (void)ws_size; (void)in_sizes; (void)n_in; (void)out_size;

    dim3 b256(256);
    const dim3 gGemm(8, 64);
    wt_kernel<<<dim3(16, 16, 5), b256, 0, stream>>>(Wq, Wk, Wv, Wo, Wt, pad, maskAndB);
    gemm_proj<<<gGemm, b256, 0, stream>>>(q, Wt + (size_t)0 * 1024 * 1024, QP, 0.125f * LOG2E, 0);
    gemm_proj<<<gGemm, b256, 0, stream>>>(k, Wt + (size_t)1 * 1024 * 1024, KP, 1.0f, 0);
    gemm_proj<<<gGemm, b256, 0, stream>>>(v, Wt + (size_t)2 * 1024 * 1024, VTb, 1.0f, 1);
    attn_kernel<<<gGemm, dim3(512), 0, stream>>>(QP, KP, VTb, maskAndB, AO);
    gemm_out<<<gGemm, b256, 0, stream>>>(AO, Wt + (size_t)3 * 1024 * 1024, out);
}

// Round 20
// 195.493 us; speedup vs baseline: 3.2137x; 1.0423x over previous
//
#include <hip/hip_runtime.h>
#include <hip/hip_bf16.h>

#define TQ 2048
#define HIDDEN 1024
#define NB 4
#define NH 16
#define DH 64
#define BHN (NB*NH)   // 64
#define LOG2E 1.44269504f

typedef __attribute__((ext_vector_type(4))) float f32x4;
typedef __attribute__((ext_vector_type(8))) short s16x8;

#if __has_builtin(__builtin_amdgcn_exp2f)
#define EXP2(x) __builtin_amdgcn_exp2f(x)
#else
#define EXP2(x) exp2f(x)
#endif

__device__ inline unsigned short f2bf(float f) {
    union { float f; unsigned int u; } x; x.f = f;
    unsigned int r = x.u + 0x7fffu + ((x.u >> 16) & 1u);
    return (unsigned short)(r >> 16);
}

__device__ inline unsigned int pkbf(float a, float b) {
    __hip_bfloat162 h = __float22bfloat162_rn(make_float2(a, b));
    return *reinterpret_cast<unsigned int*>(&h);
}

union PBU { uint4 u4; s16x8 v; };

// async global->LDS, 16B per lane; lds dst must be wave-uniform base
#define GLL16(gsrc, ldst) \
    __builtin_amdgcn_global_load_lds( \
        (const __attribute__((address_space(1))) unsigned int*)(gsrc), \
        (__attribute__((address_space(3))) unsigned int*)(ldst), 16, 0, 0)

// ---------------------------------------------------------------------------
// Weight transpose+convert + mask prep fused: z in {0..3}: Wt[n][k]=bf16(W[k][n]);
// z==4: maskAndB ushort [4][2048] in pb-slot-PERMUTED order (0xFFFF keep / 0).
// ---------------------------------------------------------------------------
__global__ __launch_bounds__(256) void wt_kernel(const float* W0, const float* W1,
                                                 const float* W2, const float* W3,
                                                 unsigned short* Wt,
                                                 const int* __restrict__ pad,
                                                 unsigned short* __restrict__ maskAndB) {
    if (blockIdx.z == 4) {
        int lin = blockIdx.y * 16 + blockIdx.x;
        if (lin < 32) {
            int p = lin * 256 + threadIdx.x;   // 0..8191
            int r = p >> 11, off = p & 2047;
            int o6 = off & 63;
            int ks = o6 >> 5, k32 = o6 & 31;
            int lg = k32 >> 3, j = k32 & 7;
            int key = (off & ~63) | (ks * 32 + ((j >> 2) << 4) + (lg << 2) + (j & 3));
            maskAndB[p] = pad[r * 2048 + key] ? (unsigned short)0 : (unsigned short)0xFFFF;
        }
        return;
    }
    const float* W = (blockIdx.z == 0) ? W0 : (blockIdx.z == 1) ? W1
                    : (blockIdx.z == 2) ? W2 : W3;
    unsigned short* out = Wt + (size_t)blockIdx.z * HIDDEN * HIDDEN;
    __shared__ float tile[64][68];
    int t = threadIdx.x;
    int k0 = blockIdx.y * 64, n0 = blockIdx.x * 64;
#pragma unroll
    for (int i = 0; i < 4; i++) {
        int r = (t >> 4) + i * 16;
        int c = (t & 15) * 4;
        float4 v = *(const float4*)(W + (size_t)(k0 + r) * HIDDEN + n0 + c);
        tile[r][c] = v.x; tile[r][c+1] = v.y; tile[r][c+2] = v.z; tile[r][c+3] = v.w;
    }
    __syncthreads();
#pragma unroll
    for (int i = 0; i < 4; i++) {
        int n = (t >> 4) + i * 16;
        int kc = (t & 15) * 4;
        ushort4 o;
        o.x = f2bf(tile[kc+0][n]); o.y = f2bf(tile[kc+1][n]);
        o.z = f2bf(tile[kc+2][n]); o.w = f2bf(tile[kc+3][n]);
        *(ushort4*)(out + (size_t)(n0 + n) * HIDDEN + k0 + kc) = o;
    }
}

// ---------------------------------------------------------------------------
// Projection GEMM, BK=64 (R12-proven): A f32 [8192][1024] x Wt bf16 [n][k].
// 128x128 tile, grid (8,64). A staged f32 (32KB) via global_load_lds with
// pre-swizzled source (16 slots/row, slot^(row&15)); B bf16 (16KB,
// 8 slots/row, slot^(row&7)). Fragments cvt f32->bf16 on read.
// vt=0: out bf16 head-split [B*H][T][D], scaled
// vt=1: out bf16 head-split transposed [B*H][D][T]
// ---------------------------------------------------------------------------
__global__ __launch_bounds__(256) void gemm_proj(const float* __restrict__ A,
                                                 const unsigned short* __restrict__ Bt,
                                                 unsigned short* __restrict__ outb,
                                                 float scale, int vt) {
    __shared__ alignas(16) float As[128 * 64];            // 32 KB
    __shared__ alignas(16) unsigned short Bs[128 * 64];   // 16 KB
    const int t = threadIdx.x;
    const int wave = t >> 6, lane = t & 63;
    const int wr = wave >> 1, wc = wave & 1;
    const int lr = lane & 15, lg = lane >> 4;
    const int linear = blockIdx.x + 8 * blockIdx.y;          // 0..511
    const int tile = ((linear & 7) << 6) | (linear >> 3);
    const int m0 = (tile >> 3) * 128, n0 = (tile & 7) * 128;

    size_t gA[8];
#pragma unroll
    for (int i = 0; i < 8; i++) {
        int f = i * 256 + t;
        int row = f >> 4, sg = (f & 15) ^ (row & 15);
        gA[i] = (size_t)(m0 + row) * HIDDEN + sg * 4;
    }
    size_t gB[4];
#pragma unroll
    for (int i = 0; i < 4; i++) {
        int f = i * 256 + t;
        int row = f >> 3, sg = (f & 7) ^ (row & 7);
        gB[i] = (size_t)(n0 + row) * HIDDEN + sg * 8;
    }

    f32x4 acc[4][4] = {};

    for (int k0 = 0; k0 < HIDDEN; k0 += 64) {
        __syncthreads();
#pragma unroll
        for (int i = 0; i < 8; i++)
            GLL16(A + gA[i] + k0, &As[(size_t)(i * 256 + wave * 64) * 4]);
#pragma unroll
        for (int i = 0; i < 4; i++)
            GLL16(Bt + gB[i] + k0, &Bs[(size_t)(i * 256 + wave * 64) * 8]);
        __syncthreads();
#pragma unroll
        for (int q = 0; q < 2; q++) {
            s16x8 af[4], bfr[4];
#pragma unroll
            for (int mi = 0; mi < 4; mi++) {
                int row = wr * 64 + mi * 16 + lr;
                int s0 = (q * 8 + lg * 2) ^ (row & 15);
                int s1 = (q * 8 + lg * 2 + 1) ^ (row & 15);
                float4 a0 = *(const float4*)(&As[row * 64 + s0 * 4]);
                float4 a1 = *(const float4*)(&As[row * 64 + s1 * 4]);
                PBU u;
                u.u4.x = pkbf(a0.x, a0.y); u.u4.y = pkbf(a0.z, a0.w);
                u.u4.z = pkbf(a1.x, a1.y); u.u4.w = pkbf(a1.z, a1.w);
                af[mi] = u.v;
            }
#pragma unroll
            for (int ni = 0; ni < 4; ni++) {
                int row = wc * 64 + ni * 16 + lr;
                int s = (q * 4 + lg) ^ (row & 7);
                bfr[ni] = *(const s16x8*)(&Bs[row * 64 + s * 8]);
            }
#pragma unroll
            for (int mi = 0; mi < 4; mi++)
#pragma unroll
                for (int ni = 0; ni < 4; ni++)
                    acc[mi][ni] = __builtin_amdgcn_mfma_f32_16x16x32_bf16(af[mi], bfr[ni], acc[mi][ni], 0, 0, 0);
        }
    }

    if (vt == 0) {
#pragma unroll
        for (int mi = 0; mi < 4; mi++)
#pragma unroll
            for (int ni = 0; ni < 4; ni++)
#pragma unroll
                for (int j = 0; j < 4; j++) {
                    int m = m0 + wr * 64 + mi * 16 + lg * 4 + j;
                    int n = n0 + wc * 64 + ni * 16 + lr;
                    int b = m >> 11, tt = m & (TQ - 1);
                    int h = n >> 6, d = n & 63;
                    outb[((size_t)(b * NH + h) * TQ + tt) * DH + d] = f2bf(acc[mi][ni][j] * scale);
                }
    } else {
#pragma unroll
        for (int mi = 0; mi < 4; mi++)
#pragma unroll
            for (int ni = 0; ni < 4; ni++) {
                int m = m0 + wr * 64 + mi * 16 + lg * 4;
                int n = n0 + wc * 64 + ni * 16 + lr;
                int b = m >> 11, tt = m & (TQ - 1);
                int h = n >> 6, d = n & 63;
                ushort4 pk;
                pk.x = f2bf(acc[mi][ni][0] * scale);
                pk.y = f2bf(acc[mi][ni][1] * scale);
                pk.z = f2bf(acc[mi][ni][2] * scale);
                pk.w = f2bf(acc[mi][ni][3] * scale);
                *(ushort4*)(outb + ((size_t)(b * NH + h) * DH + d) * TQ + tt) = pk;
            }
    }
}

// ---------------------------------------------------------------------------
// Final GEMM, BK=64 (R12-proven): A bf16 [8192][1024] x Wt bf16 -> out f32.
// ---------------------------------------------------------------------------
__global__ __launch_bounds__(256) void gemm_out(const unsigned short* __restrict__ A,
                                                const unsigned short* __restrict__ Bt,
                                                float* __restrict__ out) {
    __shared__ alignas(16) unsigned short As[128 * 64];   // 16 KB
    __shared__ alignas(16) unsigned short Bs[128 * 64];   // 16 KB
    const int t = threadIdx.x;
    const int wave = t >> 6, lane = t & 63;
    const int wr = wave >> 1, wc = wave & 1;
    const int lr = lane & 15, lg = lane >> 4;
    const int linear = blockIdx.x + 8 * blockIdx.y;
    const int tile = ((linear & 7) << 6) | (linear >> 3);
    const int m0 = (tile >> 3) * 128, n0 = (tile & 7) * 128;

    size_t gA[4], gB[4];
#pragma unroll
    for (int i = 0; i < 4; i++) {
        int f = i * 256 + t;
        int row = f >> 3, sg = (f & 7) ^ (row & 7);
        gA[i] = (size_t)(m0 + row) * HIDDEN + sg * 8;
        gB[i] = (size_t)(n0 + row) * HIDDEN + sg * 8;
    }

    f32x4 acc[4][4] = {};

    for (int k0 = 0; k0 < HIDDEN; k0 += 64) {
        __syncthreads();
#pragma unroll
        for (int i = 0; i < 4; i++) {
            GLL16(A + gA[i] + k0, &As[(size_t)(i * 256 + wave * 64) * 8]);
            GLL16(Bt + gB[i] + k0, &Bs[(size_t)(i * 256 + wave * 64) * 8]);
        }
        __syncthreads();
#pragma unroll
        for (int q = 0; q < 2; q++) {
            s16x8 af[4], bfr[4];
#pragma unroll
            for (int mi = 0; mi < 4; mi++) {
                int row = wr * 64 + mi * 16 + lr;
                int s = (q * 4 + lg) ^ (row & 7);
                af[mi] = *(const s16x8*)(&As[row * 64 + s * 8]);
            }
#pragma unroll
            for (int ni = 0; ni < 4; ni++) {
                int row = wc * 64 + ni * 16 + lr;
                int s = (q * 4 + lg) ^ (row & 7);
                bfr[ni] = *(const s16x8*)(&Bs[row * 64 + s * 8]);
            }
#pragma unroll
            for (int mi = 0; mi < 4; mi++)
#pragma unroll
                for (int ni = 0; ni < 4; ni++)
                    acc[mi][ni] = __builtin_amdgcn_mfma_f32_16x16x32_bf16(af[mi], bfr[ni], acc[mi][ni], 0, 0, 0);
        }
    }
#pragma unroll
    for (int mi = 0; mi < 4; mi++)
#pragma unroll
        for (int ni = 0; ni < 4; ni++)
#pragma unroll
            for (int j = 0; j < 4; j++) {
                int m = m0 + wr * 64 + mi * 16 + lg * 4 + j;
                int n = n0 + wc * 64 + ni * 16 + lr;
                out[(size_t)m * HIDDEN + n] = acc[mi][ni][j];
            }
}

// ---------------------------------------------------------------------------
// Flash attention v12 (R15/R17-proven, 85 us): 4 waves x 64 q-rows (u=4),
// grid (8,64)=512 -> 2 independent blocks/CU. K/V fragment reads amortized
// over 64 q-rows/wave. KVBLK=64 dbuf, fixed-shift softmax, XCD-chunked bh
// swizzle, swapped QK, in-lane P packing, P-AND mask, ones-MFMA denominator.
// No setprio (R16: regression); no key-split (R18/R19: regression).
// ---------------------------------------------------------------------------
__global__ __launch_bounds__(256, 2) void attn_kernel(
        const unsigned short* __restrict__ QP,
        const unsigned short* __restrict__ KP,
        const unsigned short* __restrict__ VT,
        const unsigned short* __restrict__ maskAndB,
        unsigned short* __restrict__ AO) {
    __shared__ alignas(16) unsigned short Ks[2][64 * 72];
    __shared__ alignas(16) unsigned short Vs[2][64 * 72];
    const int t = threadIdx.x, wave = t >> 6, lane = t & 63;
    const int lr = lane & 15, lg = lane >> 4;
    const int linear = blockIdx.x + 8 * blockIdx.y;          // 0..511
    const int bh = ((linear & 7) << 3) | ((linear >> 3) & 7);
    const int qb = linear >> 6;                               // 0..7
    const int q0 = qb * 256 + wave * 64;
    const unsigned short* Qb = QP + (size_t)bh * TQ * DH;
    const unsigned short* Kb = KP + (size_t)bh * TQ * DH;
    const unsigned short* Vb = VT + (size_t)bh * DH * TQ;
    const unsigned short* mrow = maskAndB + (bh & (NB - 1)) * TQ;

    const short ob = (short)0x3F80;                    // bf16 1.0
    const s16x8 ones = {ob, ob, ob, ob, ob, ob, ob, ob};

    s16x8 qf[4][2];
#pragma unroll
    for (int u = 0; u < 4; u++)
#pragma unroll
        for (int hh = 0; hh < 2; hh++)
            qf[u][hh] = *(const s16x8*)(Qb + (size_t)(q0 + u * 16 + lr) * DH + hh * 32 + lg * 8);

    // staging: 2 K-chunks + 2 V-chunks per thread (256 thr x 2 = 512 chunks)
    const int c0 = t, c1 = 256 + t;
    const int sr0 = c0 >> 3, scl0 = (c0 & 7) * 8;
    const int sr1 = c1 >> 3, scl1 = (c1 & 7) * 8;
    const unsigned short* kA0 = Kb + sr0 * DH + scl0;
    const unsigned short* kA1 = Kb + sr1 * DH + scl1;
    const unsigned short* vA0 = Vb + (size_t)sr0 * TQ + scl0;
    const unsigned short* vA1 = Vb + (size_t)sr1 * TQ + scl1;
    const int ksO0 = sr0 * 72 + scl0, ksO1 = sr1 * 72 + scl1;
    const int cc0 = c0 & 7, cc1 = c1 & 7;
    const int vg0 = ((cc0 & 4) << 1) + ((cc0 & 1) << 2) + ((cc0 >> 1) & 1);
    const int vg1 = ((cc1 & 4) << 1) + ((cc1 & 1) << 2) + ((cc1 >> 1) & 1);
    const int vO0 = sr0 * 72 + vg0 * 4, vO1 = sr1 * 72 + vg1 * 4;

    uint4 kr0, kr1, vr0, vr1;
#define LOAD_TILE(kt_) do { \
        kr0 = *(const uint4*)(kA0 + (size_t)(kt_) * 4096); \
        kr1 = *(const uint4*)(kA1 + (size_t)(kt_) * 4096); \
        vr0 = *(const uint4*)(vA0 + (size_t)(kt_) * 64); \
        vr1 = *(const uint4*)(vA1 + (size_t)(kt_) * 64); \
    } while (0)
#define STORE_TILE(b_) do { \
        *(uint4*)(&Ks[b_][ksO0]) = kr0; \
        *(uint4*)(&Ks[b_][ksO1]) = kr1; \
        *(uint2*)(&Vs[b_][vO0])     = make_uint2(vr0.x, vr0.y); \
        *(uint2*)(&Vs[b_][vO0 + 8]) = make_uint2(vr0.z, vr0.w); \
        *(uint2*)(&Vs[b_][vO1])     = make_uint2(vr1.x, vr1.y); \
        *(uint2*)(&Vs[b_][vO1 + 8]) = make_uint2(vr1.z, vr1.w); \
    } while (0)

    f32x4 o[4][4] = {};
    f32x4 osum[4] = {};

    LOAD_TILE(0);
    STORE_TILE(0);

    const int NT = TQ / 64;
    for (int kt = 0; kt < NT; kt++) {
        __syncthreads();
        const int cur = kt & 1;
        if (kt + 1 < NT) LOAD_TILE(kt + 1);
        uint4 ma0 = *(const uint4*)(mrow + kt * 64 + lg * 8);
        uint4 ma1 = *(const uint4*)(mrow + kt * 64 + 32 + lg * 8);

        // S^T: z[u][ni][r], q=lr, k=ni*16+lg*4+r; kf shared across 4 u
        f32x4 z[4][4] = {};
#pragma unroll
        for (int ni = 0; ni < 4; ni++) {
            s16x8 kf0 = *(const s16x8*)(&Ks[cur][(ni * 16 + lr) * 72 + lg * 8]);
            s16x8 kf1 = *(const s16x8*)(&Ks[cur][(ni * 16 + lr) * 72 + 32 + lg * 8]);
#pragma unroll
            for (int u = 0; u < 4; u++) {
                z[u][ni] = __builtin_amdgcn_mfma_f32_16x16x32_bf16(kf0, qf[u][0], z[u][ni], 0, 0, 0);
                z[u][ni] = __builtin_amdgcn_mfma_f32_16x16x32_bf16(kf1, qf[u][1], z[u][ni], 0, 0, 0);
            }
        }

        // P = exp2(z) (fixed-shift softmax), pack in-lane, AND mask
        PBU pb[4][2];
#pragma unroll
        for (int u = 0; u < 4; u++) {
#pragma unroll
            for (int ni = 0; ni < 4; ni++)
#pragma unroll
                for (int rr = 0; rr < 4; rr++)
                    z[u][ni][rr] = EXP2(z[u][ni][rr]);
#pragma unroll
            for (int ks = 0; ks < 2; ks++) {
                pb[u][ks].u4.x = pkbf(z[u][2 * ks][0], z[u][2 * ks][1]);
                pb[u][ks].u4.y = pkbf(z[u][2 * ks][2], z[u][2 * ks][3]);
                pb[u][ks].u4.z = pkbf(z[u][2 * ks + 1][0], z[u][2 * ks + 1][1]);
                pb[u][ks].u4.w = pkbf(z[u][2 * ks + 1][2], z[u][2 * ks + 1][3]);
            }
            pb[u][0].u4.x &= ma0.x; pb[u][0].u4.y &= ma0.y;
            pb[u][0].u4.z &= ma0.z; pb[u][0].u4.w &= ma0.w;
            pb[u][1].u4.x &= ma1.x; pb[u][1].u4.y &= ma1.y;
            pb[u][1].u4.z &= ma1.z; pb[u][1].u4.w &= ma1.w;
        }

        // O^T += V^T x P^T ; denominator via const-ones MFMA (pb pre-masked)
#pragma unroll
        for (int di = 0; di < 4; di++)
#pragma unroll
            for (int ks = 0; ks < 2; ks++) {
                s16x8 vf = *(const s16x8*)(&Vs[cur][(di * 16 + lr) * 72 + ks * 32 + lg * 8]);
#pragma unroll
                for (int u = 0; u < 4; u++)
                    o[u][di] = __builtin_amdgcn_mfma_f32_16x16x32_bf16(vf, pb[u][ks].v, o[u][di], 0, 0, 0);
            }
#pragma unroll
        for (int u = 0; u < 4; u++) {
            osum[u] = __builtin_amdgcn_mfma_f32_16x16x32_bf16(ones, pb[u][0].v, osum[u], 0, 0, 0);
            osum[u] = __builtin_amdgcn_mfma_f32_16x16x32_bf16(ones, pb[u][1].v, osum[u], 0, 0, 0);
        }

        if (kt + 1 < NT) STORE_TILE((kt + 1) & 1);
    }

    // epilogue: lane holds q=lr; osum[u][*] = denominator for that q
    const int b = bh >> 4, h = bh & 15;
#pragma unroll
    for (int u = 0; u < 4; u++) {
        float inv = 1.f / osum[u][0];
        int tt = q0 + u * 16 + lr;
#pragma unroll
        for (int di = 0; di < 4; di++) {
            uint2 w;
            w.x = pkbf(o[u][di][0] * inv, o[u][di][1] * inv);
            w.y = pkbf(o[u][di][2] * inv, o[u][di][3] * inv);
            *(uint2*)(AO + (size_t)(b * TQ + tt) * HIDDEN + h * 64 + di * 16 + lg * 4) = w;
        }
    }
#undef LOAD_TILE
#undef STORE_TILE
}

// ---------------------------------------------------------------------------
extern "C" void kernel_launch(void* const* d_in, const int* in_sizes, int n_in,
                              void* d_out, int out_size, void* d_ws, size_t ws_size,
                              hipStream_t stream) {
    const float* q  = (const float*)d_in[0];
    const float* k  = (const float*)d_in[1];
    const float* v  = (const float*)d_in[2];
    const int* pad  = (const int*)d_in[3];
    const float* Wq = (const float*)d_in[4];
    const float* Wk = (const float*)d_in[5];
    const float* Wv = (const float*)d_in[6];
    const float* Wo = (const float*)d_in[7];
    float* out = (float*)d_out;

    // ws (bf16 elems): Wt 4M | AO 8.39M | QP | KP | VT | maskAndB
    unsigned short* ws = (unsigned short*)d_ws;
    unsigned short* Wt = ws;
    unsigned short* AO = ws + (size_t)4 * 1024 * 1024;
    unsigned short* QP = AO + (size_t)BHN * TQ * DH;
    unsigned short* KP = QP + (size_t)BHN * TQ * DH;
    unsigned short* VTb = KP + (size_t)BHN * TQ * DH;
    unsigned short* maskAndB = VTb + (size_t)BHN * TQ * DH;
    (void)ws_size; (void)in_sizes; (void)n_in; (void)out_size;

    dim3 b256(256);
    const dim3 gGemm(8, 64);
    wt_kernel<<<dim3(16, 16, 5), b256, 0, stream>>>(Wq, Wk, Wv, Wo, Wt, pad, maskAndB);
    gemm_proj<<<gGemm, b256, 0, stream>>>(q, Wt + (size_t)0 * 1024 * 1024, QP, 0.125f * LOG2E, 0);
    gemm_proj<<<gGemm, b256, 0, stream>>>(k, Wt + (size_t)1 * 1024 * 1024, KP, 1.0f, 0);
    gemm_proj<<<gGemm, b256, 0, stream>>>(v, Wt + (size_t)2 * 1024 * 1024, VTb, 1.0f, 1);
    attn_kernel<<<gGemm, b256, 0, stream>>>(QP, KP, VTb, maskAndB, AO);
    gemm_out<<<gGemm, b256, 0, stream>>>(AO, Wt + (size_t)3 * 1024 * 1024, out);
}